// Round 5
// baseline (452.946 us; speedup 1.0000x reference)
//
#include <hip/hip_runtime.h>

#define S 64
#define SP (S + 1)
#define E_EDGES 256
#define NT 512
#define N_NODES 32768
#define CHUNK_NODES 16
#define NCHUNKS (N_NODES / CHUNK_NODES)  // 2048

__device__ __forceinline__ float v_rcp(float x) {
  float r;
  asm("v_rcp_f32 %0, %1" : "=v"(r) : "v"(x));
  return r;
}

// tanh(x) = 1 - 2/(exp2(2*log2e*x)+1); exact at +-inf, ~1e-7 rel err, branch-free
__device__ __forceinline__ float tanh_term(float x) {
  float t = __builtin_amdgcn_exp2f(x * 2.88539008177793f);
  return fmaf(-2.0f, v_rcp(t + 1.0f), 1.0f);
}

// zero done flags + copy counter, build touched-node bitmap
__global__ void init_kernel(const int* __restrict__ edges, int* __restrict__ done,
                            unsigned int* __restrict__ bitmap, int* __restrict__ ctr) {
  const int tid = threadIdx.x;  // 1024 threads, 1 block
  if (tid < E_EDGES) done[tid] = 0;
  if (tid == 0) *ctr = 0;
  bitmap[tid] = 0u;  // 1024 words = 32768 bits
  __syncthreads();
  if (tid < 2 * E_EDGES) {
    int node = edges[tid];
    atomicOr(&bitmap[node >> 5], 1u << (node & 31));
  }
}

__global__ __launch_bounds__(NT, 1) void fused_kernel(
    const float* __restrict__ inputs,
    const int* __restrict__ masks,
    const int* __restrict__ edges,
    const float* __restrict__ Wq,
    const float* __restrict__ Wk,
    const float* __restrict__ wv,
    const float* __restrict__ Wfc,
    const float* __restrict__ bfc,
    float* __restrict__ out,
    int* __restrict__ done,
    const unsigned int* __restrict__ bitmap,
    int* __restrict__ copyCtr) {
  const int tid = threadIdx.x;
  const int e = blockIdx.x;

  __shared__ float sWq[S][SP];
  __shared__ float sWk[S][SP];
  __shared__ float sWfc[S][2 * S + 1];
  __shared__ float sEx[S][SP];
  __shared__ float sEy[S][SP];
  __shared__ float sQ[S][SP];
  __shared__ float sK[S][SP];
  __shared__ float sP[S][SP];
  __shared__ float swv[S];
  __shared__ float sbfc[S];
  __shared__ unsigned int sBitmap[N_NODES / 32];  // 4 KB
  __shared__ int sMeta[6];  // depA, depB, validA, validB, ready, chunk

  const int a = edges[e];
  const int b = edges[E_EDGES + e];

  if (tid < 2) sMeta[tid] = -1;
  __syncthreads();
  // latest earlier edge touching node a / node b
  if (tid < e) {
    int xa = edges[tid];
    int yb = edges[E_EDGES + tid];
    if (xa == a || yb == a) atomicMax(&sMeta[0], tid);
    if (xa == b || yb == b) atomicMax(&sMeta[1], tid);
  }

  // stage weights + bitmap (state-independent)
#pragma unroll
  for (int k = 0; k < 8; ++k) {
    int idx = tid + k * NT;  // 0..4095
    sWq[idx >> 6][idx & 63] = Wq[idx];
    sWk[idx >> 6][idx & 63] = Wk[idx];
  }
#pragma unroll
  for (int k = 0; k < 16; ++k) {
    int idx = tid + k * NT;  // 0..8191
    sWfc[idx >> 7][idx & 127] = Wfc[idx];
  }
  if (tid < S) { swv[tid] = wv[tid]; sbfc[tid] = bfc[tid]; }
  sBitmap[tid] = bitmap[tid];
  sBitmap[tid + NT] = bitmap[tid + NT];

  // valid lengths
  const int lane = tid & 63;
  const int wave = tid >> 6;
  int mv = 0;
  if (wave == 0) mv = masks[(size_t)a * S + lane];
  else if (wave == 1) mv = masks[(size_t)b * S + lane];
#pragma unroll
  for (int d = 1; d < 64; d <<= 1) mv += __shfl_xor(mv, d, 64);
  if (tid == 0) sMeta[2] = mv;
  if (tid == 64) sMeta[3] = mv;

  __syncthreads();
  const int depA = sMeta[0], depB = sMeta[1];
  const int validA = sMeta[2], validB = sMeta[3];

  // copy one 16-node chunk = 256 KB CONTIGUOUS region.
  // 2 iterations of {16 float4 loads in flight (256B/thread, one contiguous
  // 16KB span per wave per load), then 16 stores predicated by a WAVE-UNIFORM
  // scalar bitmap test: node = (k*512+tid)>>10 == k>>1 exactly}.
  auto copy_chunk = [&](int c) {
    const size_t baseF4 = (size_t)c * (CHUNK_NODES * 1024);
    const int nodeBase = c * CHUNK_NODES;
    const float4* __restrict__ src = (const float4*)inputs + baseF4;
    float4* __restrict__ dst = (float4*)out + baseF4;
#pragma unroll
    for (int half = 0; half < 2; ++half) {
      float4 v[16];
#pragma unroll
      for (int k = 0; k < 16; ++k)
        v[k] = src[half * 8192 + k * 512 + tid];
#pragma unroll
      for (int k = 0; k < 16; ++k) {
        const int node = nodeBase + half * 8 + (k >> 1);  // uniform across block
        if (!(sBitmap[node >> 5] & (1u << (node & 31))))
          dst[half * 8192 + k * 512 + tid] = v[k];
      }
    }
  };

  // wait for latest writers of our nodes; steal copy chunks while waiting
  if (depA >= 0 || depB >= 0) {
    for (;;) {
      __syncthreads();
      if (tid == 0) {
        int ok = 1;
        if (depA >= 0 &&
            __hip_atomic_load(&done[depA], __ATOMIC_ACQUIRE, __HIP_MEMORY_SCOPE_AGENT) == 0)
          ok = 0;
        if (ok && depB >= 0 &&
            __hip_atomic_load(&done[depB], __ATOMIC_ACQUIRE, __HIP_MEMORY_SCOPE_AGENT) == 0)
          ok = 0;
        sMeta[4] = ok;
        sMeta[5] = ok ? NCHUNKS : atomicAdd(copyCtr, 1);
      }
      __syncthreads();
      if (sMeta[4]) break;
      int c = sMeta[5];
      if (c < NCHUNKS) copy_chunk(c);
      else __builtin_amdgcn_s_sleep(32);
    }
  }
  __threadfence();

  // first touch reads original inputs; otherwise the chain state in out
  const float* exg = (depA >= 0) ? out + (size_t)a * (S * S) : inputs + (size_t)a * (S * S);
  const float* eyg = (depB >= 0) ? out + (size_t)b * (S * S) : inputs + (size_t)b * (S * S);
#pragma unroll
  for (int k = 0; k < 8; ++k) {
    int idx = tid + k * NT;
    sEx[idx >> 6][idx & 63] = exg[idx];
    sEy[idx >> 6][idx & 63] = eyg[idx];
  }
  __syncthreads();

  // --- thread tilings ---
  const int tyP = tid >> 4;   // 0..31 (rows 2ty, 2ty+1)
  const int txP = tid & 15;   // 0..15 (cols 4tx..)
  const int r0P = 2 * tyP;
  const int c0P = 4 * txP;

  const int rgS = tid & 31;   // score/pv rows 2rg, 2rg+1
  const int cgS = tid >> 5;   // 0..15; score cols cgS+16u (interleaved), pv cols 4cgS..
  const int r0S = 2 * rgS;
  const int c0V = 4 * cgS;

  // D[i][h] = sum_j A[i][j] * W[h][j]
  auto proj = [&](const float (*A)[SP], const float (*W)[SP], float (*D)[SP]) {
    float acc[2][4] = {{0.f, 0.f, 0.f, 0.f}, {0.f, 0.f, 0.f, 0.f}};
#pragma unroll 8
    for (int j = 0; j < S; ++j) {
      float a0 = A[r0P][j], a1 = A[r0P + 1][j];
      float w0 = W[c0P][j], w1 = W[c0P + 1][j], w2 = W[c0P + 2][j], w3 = W[c0P + 3][j];
      acc[0][0] = fmaf(a0, w0, acc[0][0]);
      acc[0][1] = fmaf(a0, w1, acc[0][1]);
      acc[0][2] = fmaf(a0, w2, acc[0][2]);
      acc[0][3] = fmaf(a0, w3, acc[0][3]);
      acc[1][0] = fmaf(a1, w0, acc[1][0]);
      acc[1][1] = fmaf(a1, w1, acc[1][1]);
      acc[1][2] = fmaf(a1, w2, acc[1][2]);
      acc[1][3] = fmaf(a1, w3, acc[1][3]);
    }
#pragma unroll
    for (int u = 0; u < 4; ++u) {
      D[r0P][c0P + u] = acc[0][u];
      D[r0P + 1][c0P + u] = acc[1][u];
    }
  };

  // scores only for c < vlen (interleaved cols -> wave load balance); vlen==0 -> uniform 1/64
  auto score_phase = [&](int vlen) {
#pragma unroll
    for (int u = 0; u < 4; ++u) {
      const int c = cgS + 16 * u;
      if (c < vlen) {
        float a0 = 0.f, a1 = 0.f;
#pragma unroll 8
        for (int h = 0; h < S; ++h) {
          float kk = sK[c][h];
          float wvh = swv[h];
          a0 = fmaf(tanh_term(sQ[r0S][h] + kk), wvh, a0);
          a1 = fmaf(tanh_term(sQ[r0S + 1][h] + kk), wvh, a1);
        }
        sP[r0S][c] = a0;
        sP[r0S + 1][c] = a1;
      } else if (vlen == 0) {
        sP[r0S][c] = 0.015625f;  // 1/64 uniform (softmax of all -1e6)
        sP[r0S + 1][c] = 0.015625f;
      }
    }
  };

  // row softmax over cols < vlen: 8 lanes per row
  auto softmax_phase = [&](int vlen) {
    if (vlen == 0) return;  // already uniform
    const int row = tid >> 3;
    const int sub = tid & 7;
    float m = -3.0e38f;
#pragma unroll
    for (int k = 0; k < 8; ++k) {
      int c = sub + 8 * k;
      if (c < vlen) m = fmaxf(m, sP[row][c]);
    }
#pragma unroll
    for (int d = 1; d < 8; d <<= 1) m = fmaxf(m, __shfl_xor(m, d, 8));
    float p[8];
    float sum = 0.f;
#pragma unroll
    for (int k = 0; k < 8; ++k) {
      int c = sub + 8 * k;
      if (c < vlen) {
        p[k] = __expf(sP[row][c] - m);
        sum += p[k];
      }
    }
#pragma unroll
    for (int d = 1; d < 8; d <<= 1) sum += __shfl_xor(sum, d, 8);
    float inv = 1.0f / sum;
#pragma unroll
    for (int k = 0; k < 8; ++k) {
      int c = sub + 8 * k;
      if (c < vlen) sP[row][c] = p[k] * inv;
    }
  };

  // D[i][j] = sum_{k<kmax} w[i][k] * V[k][j]
  auto pv_phase = [&](const float (*V)[SP], float (*D)[SP], int vlen) {
    const int kmax = (vlen > 0) ? vlen : S;
    float acc[2][4] = {{0.f, 0.f, 0.f, 0.f}, {0.f, 0.f, 0.f, 0.f}};
    for (int k = 0; k < kmax; ++k) {
      float p0 = sP[r0S][k], p1 = sP[r0S + 1][k];
      float v0 = V[k][c0V], v1 = V[k][c0V + 1], v2 = V[k][c0V + 2], v3 = V[k][c0V + 3];
      acc[0][0] = fmaf(p0, v0, acc[0][0]);
      acc[0][1] = fmaf(p0, v1, acc[0][1]);
      acc[0][2] = fmaf(p0, v2, acc[0][2]);
      acc[0][3] = fmaf(p0, v3, acc[0][3]);
      acc[1][0] = fmaf(p1, v0, acc[1][0]);
      acc[1][1] = fmaf(p1, v1, acc[1][1]);
      acc[1][2] = fmaf(p1, v2, acc[1][2]);
      acc[1][3] = fmaf(p1, v3, acc[1][3]);
    }
#pragma unroll
    for (int u = 0; u < 4; ++u) {
      D[r0S][c0V + u] = acc[0][u];
      D[r0S + 1][c0V + u] = acc[1][u];
    }
  };

  // out[h][c] = bfc[h] + sum_r Wfc[h][r]*E1[r][c] + sum_r Wfc[h][64+r]*A1[r][c]
  auto fc_phase = [&](const float (*E1)[SP], const float (*A1)[SP], float* outg) {
    float acc[2][4];
#pragma unroll
    for (int u = 0; u < 4; ++u) {
      acc[0][u] = sbfc[r0P];
      acc[1][u] = sbfc[r0P + 1];
    }
#pragma unroll 8
    for (int r = 0; r < S; ++r) {
      float w0 = sWfc[r0P][r], w1 = sWfc[r0P + 1][r];
      float e0 = E1[r][c0P], e1 = E1[r][c0P + 1], e2 = E1[r][c0P + 2], e3 = E1[r][c0P + 3];
      acc[0][0] = fmaf(w0, e0, acc[0][0]);
      acc[0][1] = fmaf(w0, e1, acc[0][1]);
      acc[0][2] = fmaf(w0, e2, acc[0][2]);
      acc[0][3] = fmaf(w0, e3, acc[0][3]);
      acc[1][0] = fmaf(w1, e0, acc[1][0]);
      acc[1][1] = fmaf(w1, e1, acc[1][1]);
      acc[1][2] = fmaf(w1, e2, acc[1][2]);
      acc[1][3] = fmaf(w1, e3, acc[1][3]);
    }
#pragma unroll 8
    for (int r = 0; r < S; ++r) {
      float w0 = sWfc[r0P][S + r], w1 = sWfc[r0P + 1][S + r];
      float e0 = A1[r][c0P], e1 = A1[r][c0P + 1], e2 = A1[r][c0P + 2], e3 = A1[r][c0P + 3];
      acc[0][0] = fmaf(w0, e0, acc[0][0]);
      acc[0][1] = fmaf(w0, e1, acc[0][1]);
      acc[0][2] = fmaf(w0, e2, acc[0][2]);
      acc[0][3] = fmaf(w0, e3, acc[0][3]);
      acc[1][0] = fmaf(w1, e0, acc[1][0]);
      acc[1][1] = fmaf(w1, e1, acc[1][1]);
      acc[1][2] = fmaf(w1, e2, acc[1][2]);
      acc[1][3] = fmaf(w1, e3, acc[1][3]);
    }
    float4 o0 = make_float4(acc[0][0], acc[0][1], acc[0][2], acc[0][3]);
    float4 o1 = make_float4(acc[1][0], acc[1][1], acc[1][2], acc[1][3]);
    *(float4*)(outg + (size_t)r0P * S + c0P) = o0;
    *(float4*)(outg + (size_t)(r0P + 1) * S + c0P) = o1;
  };

  // ---- attention 1: q from ex, kv = ey, vlen = valid[a] ----
  proj(sEx, sWq, sQ);
  proj(sEy, sWk, sK);
  __syncthreads();
  score_phase(validA);
  __syncthreads();
  softmax_phase(validA);
  __syncthreads();
  pv_phase(sEy, sQ, validA);  // sQ := y2x
  __syncthreads();
  fc_phase(sEx, sQ, out + (size_t)a * (S * S));
  __syncthreads();

  // ---- attention 2: q from ey, kv = ex, vlen = valid[b] ----
  proj(sEy, sWq, sQ);
  proj(sEx, sWk, sK);
  __syncthreads();
  score_phase(validB);
  __syncthreads();
  softmax_phase(validB);
  __syncthreads();
  pv_phase(sEx, sQ, validB);  // sQ := x2y
  __syncthreads();
  fc_phase(sEy, sQ, out + (size_t)b * (S * S));  // y written last -> wins on self-loop

  __threadfence();
  __syncthreads();
  if (tid == 0)
    __hip_atomic_store(&done[e], 1, __ATOMIC_RELEASE, __HIP_MEMORY_SCOPE_AGENT);

  // ---- drain: work-steal remaining copy chunks ----
  for (;;) {
    __syncthreads();
    if (tid == 0) sMeta[5] = atomicAdd(copyCtr, 1);
    __syncthreads();
    int c = sMeta[5];
    if (c >= NCHUNKS) break;
    copy_chunk(c);
  }
}

extern "C" void kernel_launch(void* const* d_in, const int* in_sizes, int n_in,
                              void* d_out, int out_size, void* d_ws, size_t ws_size,
                              hipStream_t stream) {
  const float* inputs = (const float*)d_in[0];
  const int* masks = (const int*)d_in[1];
  const int* edges = (const int*)d_in[2];
  const float* Wq = (const float*)d_in[3];
  const float* Wk = (const float*)d_in[4];
  const float* wv = (const float*)d_in[5];
  const float* Wfc = (const float*)d_in[6];
  const float* bfc = (const float*)d_in[7];
  float* out = (float*)d_out;
  int* done = (int*)d_ws;                               // 256 ints
  unsigned int* bitmap = (unsigned int*)(done + E_EDGES);  // 1024 words
  int* copyCtr = (int*)(bitmap + N_NODES / 32);         // 1 int

  init_kernel<<<1, 1024, 0, stream>>>(edges, done, bitmap, copyCtr);
  fused_kernel<<<E_EDGES, NT, 0, stream>>>(inputs, masks, edges, Wq, Wk, wv, Wfc,
                                           bfc, out, done, bitmap, copyCtr);
}

// Round 6
// 435.210 us; speedup vs baseline: 1.0408x; 1.0408x over previous
//
#include <hip/hip_runtime.h>

#define S 64
#define SP (S + 1)
#define E_EDGES 256
#define NT 512
#define N_NODES 32768

__device__ __forceinline__ float v_rcp(float x) {
  float r;
  asm("v_rcp_f32 %0, %1" : "=v"(r) : "v"(x));
  return r;
}

// tanh(x) = 1 - 2/(exp2(2*log2e*x)+1); exact at +-inf, ~1e-7 rel err, branch-free
__device__ __forceinline__ float tanh_term(float x) {
  float t = __builtin_amdgcn_exp2f(x * 2.88539008177793f);
  return fmaf(-2.0f, v_rcp(t + 1.0f), 1.0f);
}

// zero done flags
__global__ void init_kernel(int* __restrict__ done) {
  done[threadIdx.x] = 0;
}

// full inputs -> out copy, zero LDS, full occupancy (8192 waves)
__global__ void copy_kernel(const float4* __restrict__ src, float4* __restrict__ dst,
                            size_t n4) {
  size_t i = (size_t)blockIdx.x * blockDim.x + threadIdx.x;
  size_t stride = (size_t)gridDim.x * blockDim.x;
  for (; i < n4; i += stride) dst[i] = src[i];
}

__global__ __launch_bounds__(NT, 1) void edge_kernel(
    const int* __restrict__ masks,
    const int* __restrict__ edges,
    const float* __restrict__ Wq,
    const float* __restrict__ Wk,
    const float* __restrict__ wv,
    const float* __restrict__ Wfc,
    const float* __restrict__ bfc,
    float* __restrict__ out,
    int* __restrict__ done) {
  const int tid = threadIdx.x;
  const int e = blockIdx.x;

  __shared__ float sWq[S][SP];
  __shared__ float sWk[S][SP];
  __shared__ float sWfc[S][2 * S + 1];
  __shared__ float sEx[S][SP];
  __shared__ float sEy[S][SP];
  __shared__ float sQ[S][SP];
  __shared__ float sK[S][SP];
  __shared__ float sP[S][SP];
  __shared__ float swv[S];
  __shared__ float sbfc[S];
  __shared__ int sMeta[4];  // depA, depB, validA, validB

  const int a = edges[e];
  const int b = edges[E_EDGES + e];

  if (tid < 2) sMeta[tid] = -1;
  __syncthreads();
  // latest earlier edge touching node a / node b (every toucher writes its node)
  if (tid < e) {
    int xa = edges[tid];
    int yb = edges[E_EDGES + tid];
    if (xa == a || yb == a) atomicMax(&sMeta[0], tid);
    if (xa == b || yb == b) atomicMax(&sMeta[1], tid);
  }

  // stage weights (state-independent)
#pragma unroll
  for (int k = 0; k < 8; ++k) {
    int idx = tid + k * NT;  // 0..4095
    sWq[idx >> 6][idx & 63] = Wq[idx];
    sWk[idx >> 6][idx & 63] = Wk[idx];
  }
#pragma unroll
  for (int k = 0; k < 16; ++k) {
    int idx = tid + k * NT;  // 0..8191
    sWfc[idx >> 7][idx & 127] = Wfc[idx];
  }
  if (tid < S) { swv[tid] = wv[tid]; sbfc[tid] = bfc[tid]; }

  // valid lengths
  const int lane = tid & 63;
  const int wave = tid >> 6;
  int mv = 0;
  if (wave == 0) mv = masks[(size_t)a * S + lane];
  else if (wave == 1) mv = masks[(size_t)b * S + lane];
#pragma unroll
  for (int d = 1; d < 64; d <<= 1) mv += __shfl_xor(mv, d, 64);
  if (tid == 0) sMeta[2] = mv;
  if (tid == 64) sMeta[3] = mv;

  __syncthreads();
  const int depA = sMeta[0], depB = sMeta[1];
  const int validA = sMeta[2], validB = sMeta[3];

  // wait for latest writers of our nodes (agent-scope acquire), then fence
  if (tid == 0 && depA >= 0) {
    while (__hip_atomic_load(&done[depA], __ATOMIC_ACQUIRE, __HIP_MEMORY_SCOPE_AGENT) == 0)
      __builtin_amdgcn_s_sleep(8);
  }
  if (tid == 64 && depB >= 0) {
    while (__hip_atomic_load(&done[depB], __ATOMIC_ACQUIRE, __HIP_MEMORY_SCOPE_AGENT) == 0)
      __builtin_amdgcn_s_sleep(8);
  }
  __syncthreads();
  __threadfence();

  // copy ran before this kernel: out holds inputs for first-touch nodes,
  // and dep-spin above guarantees chain state for re-touched nodes
  const float* exg = out + (size_t)a * (S * S);
  const float* eyg = out + (size_t)b * (S * S);
#pragma unroll
  for (int k = 0; k < 8; ++k) {
    int idx = tid + k * NT;
    sEx[idx >> 6][idx & 63] = exg[idx];
    sEy[idx >> 6][idx & 63] = eyg[idx];
  }
  __syncthreads();

  // --- thread tilings ---
  const int tyP = tid >> 4;   // 0..31 (rows 2ty, 2ty+1)
  const int txP = tid & 15;   // 0..15 (cols 4tx..)
  const int r0P = 2 * tyP;
  const int c0P = 4 * txP;

  const int rgS = tid & 31;   // score/pv rows 2rg, 2rg+1
  const int cgS = tid >> 5;   // 0..15; score cols cgS+16u (interleaved), pv cols 4cgS..
  const int r0S = 2 * rgS;
  const int c0V = 4 * cgS;

  // D[i][h] = sum_j A[i][j] * W[h][j]
  auto proj = [&](const float (*A)[SP], const float (*W)[SP], float (*D)[SP]) {
    float acc[2][4] = {{0.f, 0.f, 0.f, 0.f}, {0.f, 0.f, 0.f, 0.f}};
#pragma unroll 8
    for (int j = 0; j < S; ++j) {
      float a0 = A[r0P][j], a1 = A[r0P + 1][j];
      float w0 = W[c0P][j], w1 = W[c0P + 1][j], w2 = W[c0P + 2][j], w3 = W[c0P + 3][j];
      acc[0][0] = fmaf(a0, w0, acc[0][0]);
      acc[0][1] = fmaf(a0, w1, acc[0][1]);
      acc[0][2] = fmaf(a0, w2, acc[0][2]);
      acc[0][3] = fmaf(a0, w3, acc[0][3]);
      acc[1][0] = fmaf(a1, w0, acc[1][0]);
      acc[1][1] = fmaf(a1, w1, acc[1][1]);
      acc[1][2] = fmaf(a1, w2, acc[1][2]);
      acc[1][3] = fmaf(a1, w3, acc[1][3]);
    }
#pragma unroll
    for (int u = 0; u < 4; ++u) {
      D[r0P][c0P + u] = acc[0][u];
      D[r0P + 1][c0P + u] = acc[1][u];
    }
  };

  // scores only for c < vlen (interleaved cols -> wave load balance); vlen==0 -> uniform 1/64
  auto score_phase = [&](int vlen) {
#pragma unroll
    for (int u = 0; u < 4; ++u) {
      const int c = cgS + 16 * u;
      if (c < vlen) {
        float a0 = 0.f, a1 = 0.f;
#pragma unroll 8
        for (int h = 0; h < S; ++h) {
          float kk = sK[c][h];
          float wvh = swv[h];
          a0 = fmaf(tanh_term(sQ[r0S][h] + kk), wvh, a0);
          a1 = fmaf(tanh_term(sQ[r0S + 1][h] + kk), wvh, a1);
        }
        sP[r0S][c] = a0;
        sP[r0S + 1][c] = a1;
      } else if (vlen == 0) {
        sP[r0S][c] = 0.015625f;  // 1/64 uniform (softmax of all -1e6)
        sP[r0S + 1][c] = 0.015625f;
      }
    }
  };

  // row softmax over cols < vlen: 8 lanes per row
  auto softmax_phase = [&](int vlen) {
    if (vlen == 0) return;  // already uniform
    const int row = tid >> 3;
    const int sub = tid & 7;
    float m = -3.0e38f;
#pragma unroll
    for (int k = 0; k < 8; ++k) {
      int c = sub + 8 * k;
      if (c < vlen) m = fmaxf(m, sP[row][c]);
    }
#pragma unroll
    for (int d = 1; d < 8; d <<= 1) m = fmaxf(m, __shfl_xor(m, d, 8));
    float p[8];
    float sum = 0.f;
#pragma unroll
    for (int k = 0; k < 8; ++k) {
      int c = sub + 8 * k;
      if (c < vlen) {
        p[k] = __expf(sP[row][c] - m);
        sum += p[k];
      }
    }
#pragma unroll
    for (int d = 1; d < 8; d <<= 1) sum += __shfl_xor(sum, d, 8);
    float inv = 1.0f / sum;
#pragma unroll
    for (int k = 0; k < 8; ++k) {
      int c = sub + 8 * k;
      if (c < vlen) sP[row][c] = p[k] * inv;
    }
  };

  // D[i][j] = sum_{k<kmax} w[i][k] * V[k][j]
  auto pv_phase = [&](const float (*V)[SP], float (*D)[SP], int vlen) {
    const int kmax = (vlen > 0) ? vlen : S;
    float acc[2][4] = {{0.f, 0.f, 0.f, 0.f}, {0.f, 0.f, 0.f, 0.f}};
    for (int k = 0; k < kmax; ++k) {
      float p0 = sP[r0S][k], p1 = sP[r0S + 1][k];
      float v0 = V[k][c0V], v1 = V[k][c0V + 1], v2 = V[k][c0V + 2], v3 = V[k][c0V + 3];
      acc[0][0] = fmaf(p0, v0, acc[0][0]);
      acc[0][1] = fmaf(p0, v1, acc[0][1]);
      acc[0][2] = fmaf(p0, v2, acc[0][2]);
      acc[0][3] = fmaf(p0, v3, acc[0][3]);
      acc[1][0] = fmaf(p1, v0, acc[1][0]);
      acc[1][1] = fmaf(p1, v1, acc[1][1]);
      acc[1][2] = fmaf(p1, v2, acc[1][2]);
      acc[1][3] = fmaf(p1, v3, acc[1][3]);
    }
#pragma unroll
    for (int u = 0; u < 4; ++u) {
      D[r0S][c0V + u] = acc[0][u];
      D[r0S + 1][c0V + u] = acc[1][u];
    }
  };

  // out[h][c] = bfc[h] + sum_r Wfc[h][r]*E1[r][c] + sum_r Wfc[h][64+r]*A1[r][c]
  auto fc_phase = [&](const float (*E1)[SP], const float (*A1)[SP], float* outg) {
    float acc[2][4];
#pragma unroll
    for (int u = 0; u < 4; ++u) {
      acc[0][u] = sbfc[r0P];
      acc[1][u] = sbfc[r0P + 1];
    }
#pragma unroll 8
    for (int r = 0; r < S; ++r) {
      float w0 = sWfc[r0P][r], w1 = sWfc[r0P + 1][r];
      float e0 = E1[r][c0P], e1 = E1[r][c0P + 1], e2 = E1[r][c0P + 2], e3 = E1[r][c0P + 3];
      acc[0][0] = fmaf(w0, e0, acc[0][0]);
      acc[0][1] = fmaf(w0, e1, acc[0][1]);
      acc[0][2] = fmaf(w0, e2, acc[0][2]);
      acc[0][3] = fmaf(w0, e3, acc[0][3]);
      acc[1][0] = fmaf(w1, e0, acc[1][0]);
      acc[1][1] = fmaf(w1, e1, acc[1][1]);
      acc[1][2] = fmaf(w1, e2, acc[1][2]);
      acc[1][3] = fmaf(w1, e3, acc[1][3]);
    }
#pragma unroll 8
    for (int r = 0; r < S; ++r) {
      float w0 = sWfc[r0P][S + r], w1 = sWfc[r0P + 1][S + r];
      float e0 = A1[r][c0P], e1 = A1[r][c0P + 1], e2 = A1[r][c0P + 2], e3 = A1[r][c0P + 3];
      acc[0][0] = fmaf(w0, e0, acc[0][0]);
      acc[0][1] = fmaf(w0, e1, acc[0][1]);
      acc[0][2] = fmaf(w0, e2, acc[0][2]);
      acc[0][3] = fmaf(w0, e3, acc[0][3]);
      acc[1][0] = fmaf(w1, e0, acc[1][0]);
      acc[1][1] = fmaf(w1, e1, acc[1][1]);
      acc[1][2] = fmaf(w1, e2, acc[1][2]);
      acc[1][3] = fmaf(w1, e3, acc[1][3]);
    }
    float4 o0 = make_float4(acc[0][0], acc[0][1], acc[0][2], acc[0][3]);
    float4 o1 = make_float4(acc[1][0], acc[1][1], acc[1][2], acc[1][3]);
    *(float4*)(outg + (size_t)r0P * S + c0P) = o0;
    *(float4*)(outg + (size_t)(r0P + 1) * S + c0P) = o1;
  };

  // ---- attention 1: q from ex, kv = ey, vlen = valid[a] ----
  proj(sEx, sWq, sQ);
  proj(sEy, sWk, sK);
  __syncthreads();
  score_phase(validA);
  __syncthreads();
  softmax_phase(validA);
  __syncthreads();
  pv_phase(sEy, sQ, validA);  // sQ := y2x
  __syncthreads();
  fc_phase(sEx, sQ, out + (size_t)a * (S * S));
  __syncthreads();

  // ---- attention 2: q from ey, kv = ex, vlen = valid[b] ----
  proj(sEy, sWq, sQ);
  proj(sEx, sWk, sK);
  __syncthreads();
  score_phase(validB);
  __syncthreads();
  softmax_phase(validB);
  __syncthreads();
  pv_phase(sEx, sQ, validB);  // sQ := x2y
  __syncthreads();
  fc_phase(sEy, sQ, out + (size_t)b * (S * S));  // y written last -> wins on self-loop

  __threadfence();
  __syncthreads();
  if (tid == 0)
    __hip_atomic_store(&done[e], 1, __ATOMIC_RELEASE, __HIP_MEMORY_SCOPE_AGENT);
}

extern "C" void kernel_launch(void* const* d_in, const int* in_sizes, int n_in,
                              void* d_out, int out_size, void* d_ws, size_t ws_size,
                              hipStream_t stream) {
  const float* inputs = (const float*)d_in[0];
  const int* masks = (const int*)d_in[1];
  const int* edges = (const int*)d_in[2];
  const float* Wq = (const float*)d_in[3];
  const float* Wk = (const float*)d_in[4];
  const float* wv = (const float*)d_in[5];
  const float* Wfc = (const float*)d_in[6];
  const float* bfc = (const float*)d_in[7];
  float* out = (float*)d_out;
  int* done = (int*)d_ws;  // 256 ints

  init_kernel<<<1, E_EDGES, 0, stream>>>(done);
  // full-buffer copy at full occupancy (zero LDS): out := inputs
  size_t n4 = (size_t)out_size / 4;
  copy_kernel<<<2048, 256, 0, stream>>>((const float4*)inputs, (float4*)out, n4);
  // sequential-semantics edge updates over the copied state
  edge_kernel<<<E_EDGES, NT, 0, stream>>>(masks, edges, Wq, Wk, wv, Wfc, bfc, out, done);
}

// Round 7
// 358.677 us; speedup vs baseline: 1.2628x; 1.2134x over previous
//
#include <hip/hip_runtime.h>

#define S 64
#define SP (S + 1)
#define E_EDGES 256
#define NT 512
#define N_NODES 32768

__device__ __forceinline__ float v_rcp(float x) {
  float r;
  asm("v_rcp_f32 %0, %1" : "=v"(r) : "v"(x));
  return r;
}

// tanh(x) = 1 - 2/(exp2(2*log2e*x)+1); exact at +-inf, ~1e-7 rel err, branch-free
__device__ __forceinline__ float tanh_term(float x) {
  float t = __builtin_amdgcn_exp2f(x * 2.88539008177793f);
  return fmaf(-2.0f, v_rcp(t + 1.0f), 1.0f);
}

// zero done flags
__global__ void init_kernel(int* __restrict__ done) {
  done[threadIdx.x] = 0;
}

// full inputs -> out copy, zero LDS, full occupancy (8192 waves)
__global__ void copy_kernel(const float4* __restrict__ src, float4* __restrict__ dst,
                            size_t n4) {
  size_t i = (size_t)blockIdx.x * blockDim.x + threadIdx.x;
  size_t stride = (size_t)gridDim.x * blockDim.x;
  for (; i < n4; i += stride) dst[i] = src[i];
}

__global__ __launch_bounds__(NT, 1) void edge_kernel(
    const int* __restrict__ masks,
    const int* __restrict__ edges,
    const float* __restrict__ Wq,
    const float* __restrict__ Wk,
    const float* __restrict__ wv,
    const float* __restrict__ Wfc,
    const float* __restrict__ bfc,
    float* __restrict__ out,
    int* __restrict__ done) {
  const int tid = threadIdx.x;
  const int e = blockIdx.x;

  __shared__ float sWq[S][SP];
  __shared__ float sWk[S][SP];
  __shared__ float sWfc[S][2 * S + 1];
  __shared__ float sEx[S][SP];
  __shared__ float sEy[S][SP];
  __shared__ float sQ[S][SP];
  __shared__ float sK[S][SP];
  __shared__ float sP[S][SP];
  __shared__ float swv[S];
  __shared__ float sbfc[S];
  __shared__ int sMeta[4];  // depA, depB, validA, validB

  const int a = edges[e];
  const int b = edges[E_EDGES + e];

  if (tid < 2) sMeta[tid] = -1;
  __syncthreads();
  // latest earlier edge touching node a / node b (every toucher writes its node)
  if (tid < e) {
    int xa = edges[tid];
    int yb = edges[E_EDGES + tid];
    if (xa == a || yb == a) atomicMax(&sMeta[0], tid);
    if (xa == b || yb == b) atomicMax(&sMeta[1], tid);
  }

  // stage weights (state-independent)
#pragma unroll
  for (int k = 0; k < 8; ++k) {
    int idx = tid + k * NT;  // 0..4095
    sWq[idx >> 6][idx & 63] = Wq[idx];
    sWk[idx >> 6][idx & 63] = Wk[idx];
  }
#pragma unroll
  for (int k = 0; k < 16; ++k) {
    int idx = tid + k * NT;  // 0..8191
    sWfc[idx >> 7][idx & 127] = Wfc[idx];
  }
  if (tid < S) { swv[tid] = wv[tid]; sbfc[tid] = bfc[tid]; }

  // valid lengths
  const int lane = tid & 63;
  const int wave = tid >> 6;
  int mv = 0;
  if (wave == 0) mv = masks[(size_t)a * S + lane];
  else if (wave == 1) mv = masks[(size_t)b * S + lane];
#pragma unroll
  for (int d = 1; d < 64; d <<= 1) mv += __shfl_xor(mv, d, 64);
  if (tid == 0) sMeta[2] = mv;
  if (tid == 64) sMeta[3] = mv;

  __syncthreads();
  const int depA = sMeta[0], depB = sMeta[1];
  const int validA = sMeta[2], validB = sMeta[3];

  // wait for latest writers of our nodes.
  // RELAXED spin (no per-iteration cache invalidate), then ONE acquire load
  // to pull the coherence point into our L1/L2. Only ~8 blocks have deps.
  if (tid == 0 && depA >= 0) {
    while (__hip_atomic_load(&done[depA], __ATOMIC_RELAXED, __HIP_MEMORY_SCOPE_AGENT) == 0)
      __builtin_amdgcn_s_sleep(16);
    (void)__hip_atomic_load(&done[depA], __ATOMIC_ACQUIRE, __HIP_MEMORY_SCOPE_AGENT);
  }
  if (tid == 64 && depB >= 0) {
    while (__hip_atomic_load(&done[depB], __ATOMIC_RELAXED, __HIP_MEMORY_SCOPE_AGENT) == 0)
      __builtin_amdgcn_s_sleep(16);
    (void)__hip_atomic_load(&done[depB], __ATOMIC_ACQUIRE, __HIP_MEMORY_SCOPE_AGENT);
  }
  __syncthreads();

  // copy ran before this kernel: out holds inputs for first-touch nodes,
  // and the acquire above guarantees chain state for re-touched nodes
  const float* exg = out + (size_t)a * (S * S);
  const float* eyg = out + (size_t)b * (S * S);
#pragma unroll
  for (int k = 0; k < 8; ++k) {
    int idx = tid + k * NT;
    sEx[idx >> 6][idx & 63] = exg[idx];
    sEy[idx >> 6][idx & 63] = eyg[idx];
  }
  __syncthreads();

  // --- thread tilings ---
  const int tyP = tid >> 4;   // 0..31 (rows 2ty, 2ty+1)
  const int txP = tid & 15;   // 0..15 (cols 4tx..)
  const int r0P = 2 * tyP;
  const int c0P = 4 * txP;

  const int rgS = tid & 31;   // score/pv rows 2rg, 2rg+1
  const int cgS = tid >> 5;   // 0..15; score cols cgS+16u (interleaved), pv cols 4cgS..
  const int r0S = 2 * rgS;
  const int c0V = 4 * cgS;

  // D[i][h] = sum_j A[i][j] * W[h][j]
  auto proj = [&](const float (*A)[SP], const float (*W)[SP], float (*D)[SP]) {
    float acc[2][4] = {{0.f, 0.f, 0.f, 0.f}, {0.f, 0.f, 0.f, 0.f}};
#pragma unroll 8
    for (int j = 0; j < S; ++j) {
      float a0 = A[r0P][j], a1 = A[r0P + 1][j];
      float w0 = W[c0P][j], w1 = W[c0P + 1][j], w2 = W[c0P + 2][j], w3 = W[c0P + 3][j];
      acc[0][0] = fmaf(a0, w0, acc[0][0]);
      acc[0][1] = fmaf(a0, w1, acc[0][1]);
      acc[0][2] = fmaf(a0, w2, acc[0][2]);
      acc[0][3] = fmaf(a0, w3, acc[0][3]);
      acc[1][0] = fmaf(a1, w0, acc[1][0]);
      acc[1][1] = fmaf(a1, w1, acc[1][1]);
      acc[1][2] = fmaf(a1, w2, acc[1][2]);
      acc[1][3] = fmaf(a1, w3, acc[1][3]);
    }
#pragma unroll
    for (int u = 0; u < 4; ++u) {
      D[r0P][c0P + u] = acc[0][u];
      D[r0P + 1][c0P + u] = acc[1][u];
    }
  };

  // scores only for c < vlen (interleaved cols -> wave load balance); vlen==0 -> uniform 1/64
  auto score_phase = [&](int vlen) {
#pragma unroll
    for (int u = 0; u < 4; ++u) {
      const int c = cgS + 16 * u;
      if (c < vlen) {
        float a0 = 0.f, a1 = 0.f;
#pragma unroll 8
        for (int h = 0; h < S; ++h) {
          float kk = sK[c][h];
          float wvh = swv[h];
          a0 = fmaf(tanh_term(sQ[r0S][h] + kk), wvh, a0);
          a1 = fmaf(tanh_term(sQ[r0S + 1][h] + kk), wvh, a1);
        }
        sP[r0S][c] = a0;
        sP[r0S + 1][c] = a1;
      } else if (vlen == 0) {
        sP[r0S][c] = 0.015625f;  // 1/64 uniform (softmax of all -1e6)
        sP[r0S + 1][c] = 0.015625f;
      }
    }
  };

  // row softmax over cols < vlen: 8 lanes per row
  auto softmax_phase = [&](int vlen) {
    if (vlen == 0) return;  // already uniform
    const int row = tid >> 3;
    const int sub = tid & 7;
    float m = -3.0e38f;
#pragma unroll
    for (int k = 0; k < 8; ++k) {
      int c = sub + 8 * k;
      if (c < vlen) m = fmaxf(m, sP[row][c]);
    }
#pragma unroll
    for (int d = 1; d < 8; d <<= 1) m = fmaxf(m, __shfl_xor(m, d, 8));
    float p[8];
    float sum = 0.f;
#pragma unroll
    for (int k = 0; k < 8; ++k) {
      int c = sub + 8 * k;
      if (c < vlen) {
        p[k] = __expf(sP[row][c] - m);
        sum += p[k];
      }
    }
#pragma unroll
    for (int d = 1; d < 8; d <<= 1) sum += __shfl_xor(sum, d, 8);
    float inv = 1.0f / sum;
#pragma unroll
    for (int k = 0; k < 8; ++k) {
      int c = sub + 8 * k;
      if (c < vlen) sP[row][c] = p[k] * inv;
    }
  };

  // D[i][j] = sum_{k<kmax} w[i][k] * V[k][j]
  auto pv_phase = [&](const float (*V)[SP], float (*D)[SP], int vlen) {
    const int kmax = (vlen > 0) ? vlen : S;
    float acc[2][4] = {{0.f, 0.f, 0.f, 0.f}, {0.f, 0.f, 0.f, 0.f}};
    for (int k = 0; k < kmax; ++k) {
      float p0 = sP[r0S][k], p1 = sP[r0S + 1][k];
      float v0 = V[k][c0V], v1 = V[k][c0V + 1], v2 = V[k][c0V + 2], v3 = V[k][c0V + 3];
      acc[0][0] = fmaf(p0, v0, acc[0][0]);
      acc[0][1] = fmaf(p0, v1, acc[0][1]);
      acc[0][2] = fmaf(p0, v2, acc[0][2]);
      acc[0][3] = fmaf(p0, v3, acc[0][3]);
      acc[1][0] = fmaf(p1, v0, acc[1][0]);
      acc[1][1] = fmaf(p1, v1, acc[1][1]);
      acc[1][2] = fmaf(p1, v2, acc[1][2]);
      acc[1][3] = fmaf(p1, v3, acc[1][3]);
    }
#pragma unroll
    for (int u = 0; u < 4; ++u) {
      D[r0S][c0V + u] = acc[0][u];
      D[r0S + 1][c0V + u] = acc[1][u];
    }
  };

  // out[h][c] = bfc[h] + sum_r Wfc[h][r]*E1[r][c] + sum_r Wfc[h][64+r]*A1[r][c]
  auto fc_phase = [&](const float (*E1)[SP], const float (*A1)[SP], float* outg) {
    float acc[2][4];
#pragma unroll
    for (int u = 0; u < 4; ++u) {
      acc[0][u] = sbfc[r0P];
      acc[1][u] = sbfc[r0P + 1];
    }
#pragma unroll 8
    for (int r = 0; r < S; ++r) {
      float w0 = sWfc[r0P][r], w1 = sWfc[r0P + 1][r];
      float e0 = E1[r][c0P], e1 = E1[r][c0P + 1], e2 = E1[r][c0P + 2], e3 = E1[r][c0P + 3];
      acc[0][0] = fmaf(w0, e0, acc[0][0]);
      acc[0][1] = fmaf(w0, e1, acc[0][1]);
      acc[0][2] = fmaf(w0, e2, acc[0][2]);
      acc[0][3] = fmaf(w0, e3, acc[0][3]);
      acc[1][0] = fmaf(w1, e0, acc[1][0]);
      acc[1][1] = fmaf(w1, e1, acc[1][1]);
      acc[1][2] = fmaf(w1, e2, acc[1][2]);
      acc[1][3] = fmaf(w1, e3, acc[1][3]);
    }
#pragma unroll 8
    for (int r = 0; r < S; ++r) {
      float w0 = sWfc[r0P][S + r], w1 = sWfc[r0P + 1][S + r];
      float e0 = A1[r][c0P], e1 = A1[r][c0P + 1], e2 = A1[r][c0P + 2], e3 = A1[r][c0P + 3];
      acc[0][0] = fmaf(w0, e0, acc[0][0]);
      acc[0][1] = fmaf(w0, e1, acc[0][1]);
      acc[0][2] = fmaf(w0, e2, acc[0][2]);
      acc[0][3] = fmaf(w0, e3, acc[0][3]);
      acc[1][0] = fmaf(w1, e0, acc[1][0]);
      acc[1][1] = fmaf(w1, e1, acc[1][1]);
      acc[1][2] = fmaf(w1, e2, acc[1][2]);
      acc[1][3] = fmaf(w1, e3, acc[1][3]);
    }
    float4 o0 = make_float4(acc[0][0], acc[0][1], acc[0][2], acc[0][3]);
    float4 o1 = make_float4(acc[1][0], acc[1][1], acc[1][2], acc[1][3]);
    *(float4*)(outg + (size_t)r0P * S + c0P) = o0;
    *(float4*)(outg + (size_t)(r0P + 1) * S + c0P) = o1;
  };

  // ---- attention 1: q from ex, kv = ey, vlen = valid[a] ----
  proj(sEx, sWq, sQ);
  proj(sEy, sWk, sK);
  __syncthreads();
  score_phase(validA);
  __syncthreads();
  softmax_phase(validA);
  __syncthreads();
  pv_phase(sEy, sQ, validA);  // sQ := y2x
  __syncthreads();
  fc_phase(sEx, sQ, out + (size_t)a * (S * S));
  __syncthreads();

  // ---- attention 2: q from ey, kv = ex, vlen = valid[b] ----
  proj(sEy, sWq, sQ);
  proj(sEx, sWk, sK);
  __syncthreads();
  score_phase(validB);
  __syncthreads();
  softmax_phase(validB);
  __syncthreads();
  pv_phase(sEx, sQ, validB);  // sQ := x2y
  __syncthreads();
  fc_phase(sEy, sQ, out + (size_t)b * (S * S));  // y written last -> wins on self-loop

  // __syncthreads drains every wave's stores (vmcnt(0) before s_barrier);
  // the RELEASE store below then orders/flushes them at agent scope.
  __syncthreads();
  if (tid == 0)
    __hip_atomic_store(&done[e], 1, __ATOMIC_RELEASE, __HIP_MEMORY_SCOPE_AGENT);
}

extern "C" void kernel_launch(void* const* d_in, const int* in_sizes, int n_in,
                              void* d_out, int out_size, void* d_ws, size_t ws_size,
                              hipStream_t stream) {
  const float* inputs = (const float*)d_in[0];
  const int* masks = (const int*)d_in[1];
  const int* edges = (const int*)d_in[2];
  const float* Wq = (const float*)d_in[3];
  const float* Wk = (const float*)d_in[4];
  const float* wv = (const float*)d_in[5];
  const float* Wfc = (const float*)d_in[6];
  const float* bfc = (const float*)d_in[7];
  float* out = (float*)d_out;
  int* done = (int*)d_ws;  // 256 ints

  init_kernel<<<1, E_EDGES, 0, stream>>>(done);
  // full-buffer copy at full occupancy (zero LDS): out := inputs
  size_t n4 = (size_t)out_size / 4;
  copy_kernel<<<2048, 256, 0, stream>>>((const float4*)inputs, (float4*)out, n4);
  // sequential-semantics edge updates over the copied state
  edge_kernel<<<E_EDGES, NT, 0, stream>>>(masks, edges, Wq, Wk, wv, Wfc, bfc, out, done);
}

// Round 8
// 338.782 us; speedup vs baseline: 1.3370x; 1.0587x over previous
//
#include <hip/hip_runtime.h>

#define S 64
#define SP (S + 1)
#define E_EDGES 256
#define NT 512
#define N_NODES 32768
#define CHUNK_NODES 8
#define NCHUNKS (N_NODES / CHUNK_NODES)  // 4096

__device__ __forceinline__ float v_rcp(float x) {
  float r;
  asm("v_rcp_f32 %0, %1" : "=v"(r) : "v"(x));
  return r;
}

// tanh(x) = 1 - 2/(exp2(2*log2e*x)+1); exact at +-inf, ~1e-7 rel err, branch-free
__device__ __forceinline__ float tanh_term(float x) {
  float t = __builtin_amdgcn_exp2f(x * 2.88539008177793f);
  return fmaf(-2.0f, v_rcp(t + 1.0f), 1.0f);
}

// zero done flags + copy counter, build touched-node bitmap
__global__ void init_kernel(const int* __restrict__ edges, int* __restrict__ done,
                            unsigned int* __restrict__ bitmap, int* __restrict__ ctr) {
  const int tid = threadIdx.x;  // 1024 threads, 1 block
  if (tid < E_EDGES) done[tid] = 0;
  if (tid == 0) *ctr = 0;
  bitmap[tid] = 0u;  // 1024 words = 32768 bits
  __syncthreads();
  if (tid < 2 * E_EDGES) {
    int node = edges[tid];
    atomicOr(&bitmap[node >> 5], 1u << (node & 31));
  }
}

__global__ __launch_bounds__(NT, 1) void fused_kernel(
    const float* __restrict__ inputs,
    const int* __restrict__ masks,
    const int* __restrict__ edges,
    const float* __restrict__ Wq,
    const float* __restrict__ Wk,
    const float* __restrict__ wv,
    const float* __restrict__ Wfc,
    const float* __restrict__ bfc,
    float* __restrict__ out,
    int* __restrict__ done,
    const unsigned int* __restrict__ bitmap,
    int* __restrict__ copyCtr) {
  const int tid = threadIdx.x;
  const int e = blockIdx.x;

  __shared__ float sWq[S][SP];
  __shared__ float sWk[S][SP];
  __shared__ float sWfc[S][2 * S + 1];
  __shared__ float sEx[S][SP];
  __shared__ float sEy[S][SP];
  __shared__ float sQ[S][SP];
  __shared__ float sK[S][SP];
  __shared__ float sP[S][SP];
  __shared__ float swv[S];
  __shared__ float sbfc[S];
  __shared__ unsigned int sBitmap[N_NODES / 32];  // 4 KB
  __shared__ int sMeta[6];  // depA, depB, validA, validB, ready, chunk

  const int a = edges[e];
  const int b = edges[E_EDGES + e];

  if (tid < 2) sMeta[tid] = -1;
  __syncthreads();
  // latest earlier edge touching node a / node b (every toucher writes its node)
  if (tid < e) {
    int xa = edges[tid];
    int yb = edges[E_EDGES + tid];
    if (xa == a || yb == a) atomicMax(&sMeta[0], tid);
    if (xa == b || yb == b) atomicMax(&sMeta[1], tid);
  }

  // stage weights + bitmap (state-independent)
#pragma unroll
  for (int k = 0; k < 8; ++k) {
    int idx = tid + k * NT;  // 0..4095
    sWq[idx >> 6][idx & 63] = Wq[idx];
    sWk[idx >> 6][idx & 63] = Wk[idx];
  }
#pragma unroll
  for (int k = 0; k < 16; ++k) {
    int idx = tid + k * NT;  // 0..8191
    sWfc[idx >> 7][idx & 127] = Wfc[idx];
  }
  if (tid < S) { swv[tid] = wv[tid]; sbfc[tid] = bfc[tid]; }
  sBitmap[tid] = bitmap[tid];
  sBitmap[tid + NT] = bitmap[tid + NT];

  // valid lengths
  const int lane = tid & 63;
  const int wave = tid >> 6;
  int mv = 0;
  if (wave == 0) mv = masks[(size_t)a * S + lane];
  else if (wave == 1) mv = masks[(size_t)b * S + lane];
#pragma unroll
  for (int d = 1; d < 64; d <<= 1) mv += __shfl_xor(mv, d, 64);
  if (tid == 0) sMeta[2] = mv;
  if (tid == 64) sMeta[3] = mv;

  __syncthreads();
  const int depA = sMeta[0], depB = sMeta[1];
  const int validA = sMeta[2], validB = sMeta[3];

  // copy one 8-node chunk as 2 tight sub-iterations of 4 contiguous nodes:
  // 8 unconditional float4 loads (128 B/lane in flight, contiguous 64 KB span),
  // then 8 stores predicated on a WAVE-UNIFORM bitmap test (node = n0 + (k>>1)).
  auto copy_chunk = [&](int c) {
#pragma unroll
    for (int half = 0; half < 2; ++half) {
      const int n0 = c * CHUNK_NODES + half * 4;
      const size_t baseF4 = (size_t)n0 * 1024;
      const float4* __restrict__ src = (const float4*)inputs + baseF4;
      float4* __restrict__ dst = (float4*)out + baseF4;
      float4 v[8];
#pragma unroll
      for (int k = 0; k < 8; ++k) v[k] = src[k * 512 + tid];
#pragma unroll
      for (int k = 0; k < 8; ++k) {
        const int node = n0 + (k >> 1);  // uniform across block
        if (!(sBitmap[node >> 5] & (1u << (node & 31))))
          dst[k * 512 + tid] = v[k];
      }
    }
  };

  // wait for latest writers of our nodes: RELAXED spin (no per-iteration cache
  // invalidate), stealing copy chunks while waiting; then ONE acquire per dep.
  if (depA >= 0 || depB >= 0) {
    for (;;) {
      __syncthreads();
      if (tid == 0) {
        int ok = 1;
        if (depA >= 0 &&
            __hip_atomic_load(&done[depA], __ATOMIC_RELAXED, __HIP_MEMORY_SCOPE_AGENT) == 0)
          ok = 0;
        if (ok && depB >= 0 &&
            __hip_atomic_load(&done[depB], __ATOMIC_RELAXED, __HIP_MEMORY_SCOPE_AGENT) == 0)
          ok = 0;
        sMeta[4] = ok;
        sMeta[5] = ok ? NCHUNKS : atomicAdd(copyCtr, 1);
      }
      __syncthreads();
      if (sMeta[4]) break;
      int c = sMeta[5];
      if (c < NCHUNKS) copy_chunk(c);
      else __builtin_amdgcn_s_sleep(16);
    }
    if (tid == 0) {
      if (depA >= 0)
        (void)__hip_atomic_load(&done[depA], __ATOMIC_ACQUIRE, __HIP_MEMORY_SCOPE_AGENT);
      if (depB >= 0)
        (void)__hip_atomic_load(&done[depB], __ATOMIC_ACQUIRE, __HIP_MEMORY_SCOPE_AGENT);
    }
    __syncthreads();
  }

  // first touch reads original inputs; otherwise the chain state in out
  const float* exg = (depA >= 0) ? out + (size_t)a * (S * S) : inputs + (size_t)a * (S * S);
  const float* eyg = (depB >= 0) ? out + (size_t)b * (S * S) : inputs + (size_t)b * (S * S);
#pragma unroll
  for (int k = 0; k < 8; ++k) {
    int idx = tid + k * NT;
    sEx[idx >> 6][idx & 63] = exg[idx];
    sEy[idx >> 6][idx & 63] = eyg[idx];
  }
  __syncthreads();

  // --- thread tilings ---
  const int tyP = tid >> 4;   // 0..31 (rows 2ty, 2ty+1)
  const int txP = tid & 15;   // 0..15 (cols 4tx..)
  const int r0P = 2 * tyP;
  const int c0P = 4 * txP;

  const int rgS = tid & 31;   // score/pv rows 2rg, 2rg+1
  const int cgS = tid >> 5;   // 0..15; score cols cgS+16u (interleaved), pv cols 4cgS..
  const int r0S = 2 * rgS;
  const int c0V = 4 * cgS;

  // D[i][h] = sum_j A[i][j] * W[h][j]
  auto proj = [&](const float (*A)[SP], const float (*W)[SP], float (*D)[SP]) {
    float acc[2][4] = {{0.f, 0.f, 0.f, 0.f}, {0.f, 0.f, 0.f, 0.f}};
#pragma unroll 8
    for (int j = 0; j < S; ++j) {
      float a0 = A[r0P][j], a1 = A[r0P + 1][j];
      float w0 = W[c0P][j], w1 = W[c0P + 1][j], w2 = W[c0P + 2][j], w3 = W[c0P + 3][j];
      acc[0][0] = fmaf(a0, w0, acc[0][0]);
      acc[0][1] = fmaf(a0, w1, acc[0][1]);
      acc[0][2] = fmaf(a0, w2, acc[0][2]);
      acc[0][3] = fmaf(a0, w3, acc[0][3]);
      acc[1][0] = fmaf(a1, w0, acc[1][0]);
      acc[1][1] = fmaf(a1, w1, acc[1][1]);
      acc[1][2] = fmaf(a1, w2, acc[1][2]);
      acc[1][3] = fmaf(a1, w3, acc[1][3]);
    }
#pragma unroll
    for (int u = 0; u < 4; ++u) {
      D[r0P][c0P + u] = acc[0][u];
      D[r0P + 1][c0P + u] = acc[1][u];
    }
  };

  // scores only for c < vlen (interleaved cols -> wave load balance); vlen==0 -> uniform 1/64
  auto score_phase = [&](int vlen) {
#pragma unroll
    for (int u = 0; u < 4; ++u) {
      const int c = cgS + 16 * u;
      if (c < vlen) {
        float a0 = 0.f, a1 = 0.f;
#pragma unroll 8
        for (int h = 0; h < S; ++h) {
          float kk = sK[c][h];
          float wvh = swv[h];
          a0 = fmaf(tanh_term(sQ[r0S][h] + kk), wvh, a0);
          a1 = fmaf(tanh_term(sQ[r0S + 1][h] + kk), wvh, a1);
        }
        sP[r0S][c] = a0;
        sP[r0S + 1][c] = a1;
      } else if (vlen == 0) {
        sP[r0S][c] = 0.015625f;  // 1/64 uniform (softmax of all -1e6)
        sP[r0S + 1][c] = 0.015625f;
      }
    }
  };

  // row softmax over cols < vlen: 8 lanes per row
  auto softmax_phase = [&](int vlen) {
    if (vlen == 0) return;  // already uniform
    const int row = tid >> 3;
    const int sub = tid & 7;
    float m = -3.0e38f;
#pragma unroll
    for (int k = 0; k < 8; ++k) {
      int c = sub + 8 * k;
      if (c < vlen) m = fmaxf(m, sP[row][c]);
    }
#pragma unroll
    for (int d = 1; d < 8; d <<= 1) m = fmaxf(m, __shfl_xor(m, d, 8));
    float p[8];
    float sum = 0.f;
#pragma unroll
    for (int k = 0; k < 8; ++k) {
      int c = sub + 8 * k;
      if (c < vlen) {
        p[k] = __expf(sP[row][c] - m);
        sum += p[k];
      }
    }
#pragma unroll
    for (int d = 1; d < 8; d <<= 1) sum += __shfl_xor(sum, d, 8);
    float inv = 1.0f / sum;
#pragma unroll
    for (int k = 0; k < 8; ++k) {
      int c = sub + 8 * k;
      if (c < vlen) sP[row][c] = p[k] * inv;
    }
  };

  // D[i][j] = sum_{k<kmax} w[i][k] * V[k][j]
  auto pv_phase = [&](const float (*V)[SP], float (*D)[SP], int vlen) {
    const int kmax = (vlen > 0) ? vlen : S;
    float acc[2][4] = {{0.f, 0.f, 0.f, 0.f}, {0.f, 0.f, 0.f, 0.f}};
    for (int k = 0; k < kmax; ++k) {
      float p0 = sP[r0S][k], p1 = sP[r0S + 1][k];
      float v0 = V[k][c0V], v1 = V[k][c0V + 1], v2 = V[k][c0V + 2], v3 = V[k][c0V + 3];
      acc[0][0] = fmaf(p0, v0, acc[0][0]);
      acc[0][1] = fmaf(p0, v1, acc[0][1]);
      acc[0][2] = fmaf(p0, v2, acc[0][2]);
      acc[0][3] = fmaf(p0, v3, acc[0][3]);
      acc[1][0] = fmaf(p1, v0, acc[1][0]);
      acc[1][1] = fmaf(p1, v1, acc[1][1]);
      acc[1][2] = fmaf(p1, v2, acc[1][2]);
      acc[1][3] = fmaf(p1, v3, acc[1][3]);
    }
#pragma unroll
    for (int u = 0; u < 4; ++u) {
      D[r0S][c0V + u] = acc[0][u];
      D[r0S + 1][c0V + u] = acc[1][u];
    }
  };

  // out[h][c] = bfc[h] + sum_r Wfc[h][r]*E1[r][c] + sum_r Wfc[h][64+r]*A1[r][c]
  auto fc_phase = [&](const float (*E1)[SP], const float (*A1)[SP], float* outg) {
    float acc[2][4];
#pragma unroll
    for (int u = 0; u < 4; ++u) {
      acc[0][u] = sbfc[r0P];
      acc[1][u] = sbfc[r0P + 1];
    }
#pragma unroll 8
    for (int r = 0; r < S; ++r) {
      float w0 = sWfc[r0P][r], w1 = sWfc[r0P + 1][r];
      float e0 = E1[r][c0P], e1 = E1[r][c0P + 1], e2 = E1[r][c0P + 2], e3 = E1[r][c0P + 3];
      acc[0][0] = fmaf(w0, e0, acc[0][0]);
      acc[0][1] = fmaf(w0, e1, acc[0][1]);
      acc[0][2] = fmaf(w0, e2, acc[0][2]);
      acc[0][3] = fmaf(w0, e3, acc[0][3]);
      acc[1][0] = fmaf(w1, e0, acc[1][0]);
      acc[1][1] = fmaf(w1, e1, acc[1][1]);
      acc[1][2] = fmaf(w1, e2, acc[1][2]);
      acc[1][3] = fmaf(w1, e3, acc[1][3]);
    }
#pragma unroll 8
    for (int r = 0; r < S; ++r) {
      float w0 = sWfc[r0P][S + r], w1 = sWfc[r0P + 1][S + r];
      float e0 = A1[r][c0P], e1 = A1[r][c0P + 1], e2 = A1[r][c0P + 2], e3 = A1[r][c0P + 3];
      acc[0][0] = fmaf(w0, e0, acc[0][0]);
      acc[0][1] = fmaf(w0, e1, acc[0][1]);
      acc[0][2] = fmaf(w0, e2, acc[0][2]);
      acc[0][3] = fmaf(w0, e3, acc[0][3]);
      acc[1][0] = fmaf(w1, e0, acc[1][0]);
      acc[1][1] = fmaf(w1, e1, acc[1][1]);
      acc[1][2] = fmaf(w1, e2, acc[1][2]);
      acc[1][3] = fmaf(w1, e3, acc[1][3]);
    }
    float4 o0 = make_float4(acc[0][0], acc[0][1], acc[0][2], acc[0][3]);
    float4 o1 = make_float4(acc[1][0], acc[1][1], acc[1][2], acc[1][3]);
    *(float4*)(outg + (size_t)r0P * S + c0P) = o0;
    *(float4*)(outg + (size_t)(r0P + 1) * S + c0P) = o1;
  };

  // ---- attention 1: q from ex, kv = ey, vlen = valid[a] ----
  proj(sEx, sWq, sQ);
  proj(sEy, sWk, sK);
  __syncthreads();
  score_phase(validA);
  __syncthreads();
  softmax_phase(validA);
  __syncthreads();
  pv_phase(sEy, sQ, validA);  // sQ := y2x
  __syncthreads();
  fc_phase(sEx, sQ, out + (size_t)a * (S * S));
  __syncthreads();

  // ---- attention 2: q from ey, kv = ex, vlen = valid[b] ----
  proj(sEy, sWq, sQ);
  proj(sEx, sWk, sK);
  __syncthreads();
  score_phase(validB);
  __syncthreads();
  softmax_phase(validB);
  __syncthreads();
  pv_phase(sEx, sQ, validB);  // sQ := x2y
  __syncthreads();
  fc_phase(sEy, sQ, out + (size_t)b * (S * S));  // y written last -> wins on self-loop

  // __syncthreads drains every wave's stores; RELEASE store orders them at agent scope
  __syncthreads();
  if (tid == 0)
    __hip_atomic_store(&done[e], 1, __ATOMIC_RELEASE, __HIP_MEMORY_SCOPE_AGENT);

  // ---- drain: work-steal remaining copy chunks ----
  for (;;) {
    __syncthreads();
    if (tid == 0) sMeta[5] = atomicAdd(copyCtr, 1);
    __syncthreads();
    int c = sMeta[5];
    if (c >= NCHUNKS) break;
    copy_chunk(c);
  }
}

extern "C" void kernel_launch(void* const* d_in, const int* in_sizes, int n_in,
                              void* d_out, int out_size, void* d_ws, size_t ws_size,
                              hipStream_t stream) {
  const float* inputs = (const float*)d_in[0];
  const int* masks = (const int*)d_in[1];
  const int* edges = (const int*)d_in[2];
  const float* Wq = (const float*)d_in[3];
  const float* Wk = (const float*)d_in[4];
  const float* wv = (const float*)d_in[5];
  const float* Wfc = (const float*)d_in[6];
  const float* bfc = (const float*)d_in[7];
  float* out = (float*)d_out;
  int* done = (int*)d_ws;                                  // 256 ints
  unsigned int* bitmap = (unsigned int*)(done + E_EDGES);  // 1024 words
  int* copyCtr = (int*)(bitmap + N_NODES / 32);            // 1 int

  init_kernel<<<1, 1024, 0, stream>>>(edges, done, bitmap, copyCtr);
  fused_kernel<<<E_EDGES, NT, 0, stream>>>(inputs, masks, edges, Wq, Wk, wv, Wfc,
                                           bfc, out, done, bitmap, copyCtr);
}

// Round 9
// 288.255 us; speedup vs baseline: 1.5713x; 1.1753x over previous
//
#include <hip/hip_runtime.h>

#define S 64
#define SP (S + 1)
#define E_EDGES 256
#define NT 512
#define N_NODES 32768
#define NODES_PER_BLOCK (N_NODES / E_EDGES)  // 128
#define PAIRS (NODES_PER_BLOCK / 2)          // 64

__device__ __forceinline__ float v_rcp(float x) {
  float r;
  asm("v_rcp_f32 %0, %1" : "=v"(r) : "v"(x));
  return r;
}

// tanh(x) = 1 - 2/(exp2(2*log2e*x)+1); exact at +-inf, ~1e-7 rel err, branch-free
__device__ __forceinline__ float tanh_term(float x) {
  float t = __builtin_amdgcn_exp2f(x * 2.88539008177793f);
  return fmaf(-2.0f, v_rcp(t + 1.0f), 1.0f);
}

// zero done flags, build touched-node bitmap
__global__ void init_kernel(const int* __restrict__ edges, int* __restrict__ done,
                            unsigned int* __restrict__ bitmap) {
  const int tid = threadIdx.x;  // 1024 threads, 1 block
  if (tid < E_EDGES) done[tid] = 0;
  bitmap[tid] = 0u;  // 1024 words = 32768 bits
  __syncthreads();
  if (tid < 2 * E_EDGES) {
    int node = edges[tid];
    atomicOr(&bitmap[node >> 5], 1u << (node & 31));
  }
}

__global__ __launch_bounds__(NT, 1) void fused_kernel(
    const float* __restrict__ inputs,
    const int* __restrict__ masks,
    const int* __restrict__ edges,
    const float* __restrict__ Wq,
    const float* __restrict__ Wk,
    const float* __restrict__ wv,
    const float* __restrict__ Wfc,
    const float* __restrict__ bfc,
    float* __restrict__ out,
    int* __restrict__ done,
    const unsigned int* __restrict__ bitmap) {
  const int tid = threadIdx.x;
  const int e = blockIdx.x;

  __shared__ float sWq[S][SP];
  __shared__ float sWk[S][SP];
  __shared__ float sWfc[S][2 * S + 1];
  __shared__ float sEx[S][SP];
  __shared__ float sEy[S][SP];
  __shared__ float sQ[S][SP];
  __shared__ float sK[S][SP];
  __shared__ float sP[S][SP];
  __shared__ float swv[S];
  __shared__ float sbfc[S];
  __shared__ unsigned int sBitmap[N_NODES / 32];  // 4 KB
  __shared__ int sMeta[5];  // depA, depB, validA, validB, ready

  const int a = edges[e];
  const int b = edges[E_EDGES + e];

  if (tid < 2) sMeta[tid] = -1;
  __syncthreads();
  // latest earlier edge touching node a / node b (every toucher writes its node)
  if (tid < e) {
    int xa = edges[tid];
    int yb = edges[E_EDGES + tid];
    if (xa == a || yb == a) atomicMax(&sMeta[0], tid);
    if (xa == b || yb == b) atomicMax(&sMeta[1], tid);
  }

  // stage weights + bitmap (state-independent)
#pragma unroll
  for (int k = 0; k < 8; ++k) {
    int idx = tid + k * NT;  // 0..4095
    sWq[idx >> 6][idx & 63] = Wq[idx];
    sWk[idx >> 6][idx & 63] = Wk[idx];
  }
#pragma unroll
  for (int k = 0; k < 16; ++k) {
    int idx = tid + k * NT;  // 0..8191
    sWfc[idx >> 7][idx & 127] = Wfc[idx];
  }
  if (tid < S) { swv[tid] = wv[tid]; sbfc[tid] = bfc[tid]; }
  sBitmap[tid] = bitmap[tid];
  sBitmap[tid + NT] = bitmap[tid + NT];

  // valid lengths
  const int lane = tid & 63;
  const int wave = tid >> 6;
  int mv = 0;
  if (wave == 0) mv = masks[(size_t)a * S + lane];
  else if (wave == 1) mv = masks[(size_t)b * S + lane];
#pragma unroll
  for (int d = 1; d < 64; d <<= 1) mv += __shfl_xor(mv, d, 64);
  if (tid == 0) sMeta[2] = mv;
  if (tid == 64) sMeta[3] = mv;

  __syncthreads();
  const int depA = sMeta[0], depB = sMeta[1];
  const int validA = sMeta[2], validB = sMeta[3];

  // copy pair p of this block's static 128-node range: 4 unconditional float4
  // loads over a contiguous 32 KB span, then 4 stores predicated on a
  // WAVE-UNIFORM bitmap test. Tight load->store interleave (1x HBM writes).
  auto copy_pair = [&](int p) {
    const int n0 = e * NODES_PER_BLOCK + 2 * p;
    const int n1 = n0 + 1;
    const size_t f4 = (size_t)n0 * 1024;
    const float4* __restrict__ src = (const float4*)inputs + f4;
    float4* __restrict__ dst = (float4*)out + f4;
    float4 v0 = src[tid];
    float4 v1 = src[tid + 512];
    float4 v2 = src[tid + 1024];
    float4 v3 = src[tid + 1536];
    if (!(sBitmap[n0 >> 5] & (1u << (n0 & 31)))) {
      dst[tid] = v0;
      dst[tid + 512] = v1;
    }
    if (!(sBitmap[n1 >> 5] & (1u << (n1 & 31)))) {
      dst[tid + 1024] = v2;
      dst[tid + 1536] = v3;
    }
  };

  // dep blocks: copy own range while polling (RELAXED spin, no per-iteration
  // invalidate); then ONE acquire per dep. Dep-free blocks skip straight to edge.
  int g = 0;
  if (depA >= 0 || depB >= 0) {
    for (;;) {
      __syncthreads();
      if (tid == 0) {
        int ok = 1;
        if (depA >= 0 &&
            __hip_atomic_load(&done[depA], __ATOMIC_RELAXED, __HIP_MEMORY_SCOPE_AGENT) == 0)
          ok = 0;
        if (ok && depB >= 0 &&
            __hip_atomic_load(&done[depB], __ATOMIC_RELAXED, __HIP_MEMORY_SCOPE_AGENT) == 0)
          ok = 0;
        sMeta[4] = ok;
      }
      __syncthreads();
      if (sMeta[4]) break;
      if (g < PAIRS) {
        copy_pair(g);
        copy_pair(g + 1);
        g += 2;
      } else {
        __builtin_amdgcn_s_sleep(16);
      }
    }
    if (tid == 0) {
      if (depA >= 0)
        (void)__hip_atomic_load(&done[depA], __ATOMIC_ACQUIRE, __HIP_MEMORY_SCOPE_AGENT);
      if (depB >= 0)
        (void)__hip_atomic_load(&done[depB], __ATOMIC_ACQUIRE, __HIP_MEMORY_SCOPE_AGENT);
    }
    __syncthreads();
  }

  // first touch reads original inputs; otherwise the chain state in out
  const float* exg = (depA >= 0) ? out + (size_t)a * (S * S) : inputs + (size_t)a * (S * S);
  const float* eyg = (depB >= 0) ? out + (size_t)b * (S * S) : inputs + (size_t)b * (S * S);
#pragma unroll
  for (int k = 0; k < 8; ++k) {
    int idx = tid + k * NT;
    sEx[idx >> 6][idx & 63] = exg[idx];
    sEy[idx >> 6][idx & 63] = eyg[idx];
  }
  __syncthreads();

  // --- thread tilings ---
  const int tyP = tid >> 4;   // 0..31 (rows 2ty, 2ty+1)
  const int txP = tid & 15;   // 0..15 (cols 4tx..)
  const int r0P = 2 * tyP;
  const int c0P = 4 * txP;

  const int rgS = tid & 31;   // score/pv rows 2rg, 2rg+1
  const int cgS = tid >> 5;   // 0..15; score cols cgS+16u (interleaved), pv cols 4cgS..
  const int r0S = 2 * rgS;
  const int c0V = 4 * cgS;

  // D[i][h] = sum_j A[i][j] * W[h][j]
  auto proj = [&](const float (*A)[SP], const float (*W)[SP], float (*D)[SP]) {
    float acc[2][4] = {{0.f, 0.f, 0.f, 0.f}, {0.f, 0.f, 0.f, 0.f}};
#pragma unroll 8
    for (int j = 0; j < S; ++j) {
      float a0 = A[r0P][j], a1 = A[r0P + 1][j];
      float w0 = W[c0P][j], w1 = W[c0P + 1][j], w2 = W[c0P + 2][j], w3 = W[c0P + 3][j];
      acc[0][0] = fmaf(a0, w0, acc[0][0]);
      acc[0][1] = fmaf(a0, w1, acc[0][1]);
      acc[0][2] = fmaf(a0, w2, acc[0][2]);
      acc[0][3] = fmaf(a0, w3, acc[0][3]);
      acc[1][0] = fmaf(a1, w0, acc[1][0]);
      acc[1][1] = fmaf(a1, w1, acc[1][1]);
      acc[1][2] = fmaf(a1, w2, acc[1][2]);
      acc[1][3] = fmaf(a1, w3, acc[1][3]);
    }
#pragma unroll
    for (int u = 0; u < 4; ++u) {
      D[r0P][c0P + u] = acc[0][u];
      D[r0P + 1][c0P + u] = acc[1][u];
    }
  };

  // scores: h-outer with q0/q1 hoisted (halves Q LDS reads); cols interleaved
  // c = cgS+16u for wave load balance; vlen==0 -> uniform 1/64
  auto score_phase = [&](int vlen) {
    if (vlen == 0) {
#pragma unroll
      for (int u = 0; u < 4; ++u) {
        const int c = cgS + 16 * u;
        sP[r0S][c] = 0.015625f;
        sP[r0S + 1][c] = 0.015625f;
      }
      return;
    }
    float a0[4] = {0.f, 0.f, 0.f, 0.f};
    float a1[4] = {0.f, 0.f, 0.f, 0.f};
#pragma unroll 8
    for (int h = 0; h < S; ++h) {
      const float q0 = sQ[r0S][h];
      const float q1 = sQ[r0S + 1][h];
      const float wvh = swv[h];
#pragma unroll
      for (int u = 0; u < 4; ++u) {
        const int c = cgS + 16 * u;
        if (c < vlen) {
          const float kk = sK[c][h];
          a0[u] = fmaf(tanh_term(q0 + kk), wvh, a0[u]);
          a1[u] = fmaf(tanh_term(q1 + kk), wvh, a1[u]);
        }
      }
    }
#pragma unroll
    for (int u = 0; u < 4; ++u) {
      const int c = cgS + 16 * u;
      if (c < vlen) {
        sP[r0S][c] = a0[u];
        sP[r0S + 1][c] = a1[u];
      }
    }
  };

  // row softmax over cols < vlen: 8 lanes per row
  auto softmax_phase = [&](int vlen) {
    if (vlen == 0) return;  // already uniform
    const int row = tid >> 3;
    const int sub = tid & 7;
    float m = -3.0e38f;
#pragma unroll
    for (int k = 0; k < 8; ++k) {
      int c = sub + 8 * k;
      if (c < vlen) m = fmaxf(m, sP[row][c]);
    }
#pragma unroll
    for (int d = 1; d < 8; d <<= 1) m = fmaxf(m, __shfl_xor(m, d, 8));
    float p[8];
    float sum = 0.f;
#pragma unroll
    for (int k = 0; k < 8; ++k) {
      int c = sub + 8 * k;
      if (c < vlen) {
        p[k] = __expf(sP[row][c] - m);
        sum += p[k];
      }
    }
#pragma unroll
    for (int d = 1; d < 8; d <<= 1) sum += __shfl_xor(sum, d, 8);
    float inv = 1.0f / sum;
#pragma unroll
    for (int k = 0; k < 8; ++k) {
      int c = sub + 8 * k;
      if (c < vlen) sP[row][c] = p[k] * inv;
    }
  };

  // D[i][j] = sum_{k<kmax} w[i][k] * V[k][j]
  auto pv_phase = [&](const float (*V)[SP], float (*D)[SP], int vlen) {
    const int kmax = (vlen > 0) ? vlen : S;
    float acc[2][4] = {{0.f, 0.f, 0.f, 0.f}, {0.f, 0.f, 0.f, 0.f}};
    for (int k = 0; k < kmax; ++k) {
      float p0 = sP[r0S][k], p1 = sP[r0S + 1][k];
      float v0 = V[k][c0V], v1 = V[k][c0V + 1], v2 = V[k][c0V + 2], v3 = V[k][c0V + 3];
      acc[0][0] = fmaf(p0, v0, acc[0][0]);
      acc[0][1] = fmaf(p0, v1, acc[0][1]);
      acc[0][2] = fmaf(p0, v2, acc[0][2]);
      acc[0][3] = fmaf(p0, v3, acc[0][3]);
      acc[1][0] = fmaf(p1, v0, acc[1][0]);
      acc[1][1] = fmaf(p1, v1, acc[1][1]);
      acc[1][2] = fmaf(p1, v2, acc[1][2]);
      acc[1][3] = fmaf(p1, v3, acc[1][3]);
    }
#pragma unroll
    for (int u = 0; u < 4; ++u) {
      D[r0S][c0V + u] = acc[0][u];
      D[r0S + 1][c0V + u] = acc[1][u];
    }
  };

  // out[h][c] = bfc[h] + sum_r Wfc[h][r]*E1[r][c] + sum_r Wfc[h][64+r]*A1[r][c]
  auto fc_phase = [&](const float (*E1)[SP], const float (*A1)[SP], float* outg) {
    float acc[2][4];
#pragma unroll
    for (int u = 0; u < 4; ++u) {
      acc[0][u] = sbfc[r0P];
      acc[1][u] = sbfc[r0P + 1];
    }
#pragma unroll 8
    for (int r = 0; r < S; ++r) {
      float w0 = sWfc[r0P][r], w1 = sWfc[r0P + 1][r];
      float e0 = E1[r][c0P], e1 = E1[r][c0P + 1], e2 = E1[r][c0P + 2], e3 = E1[r][c0P + 3];
      acc[0][0] = fmaf(w0, e0, acc[0][0]);
      acc[0][1] = fmaf(w0, e1, acc[0][1]);
      acc[0][2] = fmaf(w0, e2, acc[0][2]);
      acc[0][3] = fmaf(w0, e3, acc[0][3]);
      acc[1][0] = fmaf(w1, e0, acc[1][0]);
      acc[1][1] = fmaf(w1, e1, acc[1][1]);
      acc[1][2] = fmaf(w1, e2, acc[1][2]);
      acc[1][3] = fmaf(w1, e3, acc[1][3]);
    }
#pragma unroll 8
    for (int r = 0; r < S; ++r) {
      float w0 = sWfc[r0P][S + r], w1 = sWfc[r0P + 1][S + r];
      float e0 = A1[r][c0P], e1 = A1[r][c0P + 1], e2 = A1[r][c0P + 2], e3 = A1[r][c0P + 3];
      acc[0][0] = fmaf(w0, e0, acc[0][0]);
      acc[0][1] = fmaf(w0, e1, acc[0][1]);
      acc[0][2] = fmaf(w0, e2, acc[0][2]);
      acc[0][3] = fmaf(w0, e3, acc[0][3]);
      acc[1][0] = fmaf(w1, e0, acc[1][0]);
      acc[1][1] = fmaf(w1, e1, acc[1][1]);
      acc[1][2] = fmaf(w1, e2, acc[1][2]);
      acc[1][3] = fmaf(w1, e3, acc[1][3]);
    }
    float4 o0 = make_float4(acc[0][0], acc[0][1], acc[0][2], acc[0][3]);
    float4 o1 = make_float4(acc[1][0], acc[1][1], acc[1][2], acc[1][3]);
    *(float4*)(outg + (size_t)r0P * S + c0P) = o0;
    *(float4*)(outg + (size_t)(r0P + 1) * S + c0P) = o1;
  };

  // ---- attention 1: q from ex, kv = ey, vlen = valid[a] ----
  proj(sEx, sWq, sQ);
  proj(sEy, sWk, sK);
  __syncthreads();
  score_phase(validA);
  __syncthreads();
  softmax_phase(validA);
  __syncthreads();
  pv_phase(sEy, sQ, validA);  // sQ := y2x
  __syncthreads();
  fc_phase(sEx, sQ, out + (size_t)a * (S * S));
  __syncthreads();

  // ---- attention 2: q from ey, kv = ex, vlen = valid[b] ----
  proj(sEy, sWq, sQ);
  proj(sEx, sWk, sK);
  __syncthreads();
  score_phase(validB);
  __syncthreads();
  softmax_phase(validB);
  __syncthreads();
  pv_phase(sEx, sQ, validB);  // sQ := x2y
  __syncthreads();
  fc_phase(sEy, sQ, out + (size_t)b * (S * S));  // y written last -> wins on self-loop

  // __syncthreads drains every wave's stores; RELEASE store orders them at agent scope
  __syncthreads();
  if (tid == 0)
    __hip_atomic_store(&done[e], 1, __ATOMIC_RELEASE, __HIP_MEMORY_SCOPE_AGENT);

  // ---- finish this block's static copy range (barrier-free streaming) ----
  for (; g < PAIRS; ++g) copy_pair(g);
}

extern "C" void kernel_launch(void* const* d_in, const int* in_sizes, int n_in,
                              void* d_out, int out_size, void* d_ws, size_t ws_size,
                              hipStream_t stream) {
  const float* inputs = (const float*)d_in[0];
  const int* masks = (const int*)d_in[1];
  const int* edges = (const int*)d_in[2];
  const float* Wq = (const float*)d_in[3];
  const float* Wk = (const float*)d_in[4];
  const float* wv = (const float*)d_in[5];
  const float* Wfc = (const float*)d_in[6];
  const float* bfc = (const float*)d_in[7];
  float* out = (float*)d_out;
  int* done = (int*)d_ws;                                  // 256 ints
  unsigned int* bitmap = (unsigned int*)(done + E_EDGES);  // 1024 words

  init_kernel<<<1, 1024, 0, stream>>>(edges, done, bitmap);
  fused_kernel<<<E_EDGES, NT, 0, stream>>>(inputs, masks, edges, Wq, Wk, wv, Wfc,
                                           bfc, out, done, bitmap);
}